// Round 1
// baseline (3381.352 us; speedup 1.0000x reference)
//
#include <hip/hip_runtime.h>

// Problem constants (from reference setup_inputs)
#define BN   8
#define CC   256
#define HH   64
#define WW   64
#define GG   8
#define CG   32      // C / G
#define KKK  9       // K*K
#define OO   256
#define HW   (HH*WW)
#define OFFC 144     // 2*KK*G
#define ATTC 72      // KK*G

// ---------------------------------------------------------------------------
// K0: repack w_out [O][C][3][3] -> wt_t [g][kk][cg][o]  (o contiguous)
// ---------------------------------------------------------------------------
__global__ void repack_w(const float* __restrict__ w_out, float* __restrict__ wt_t) {
    int idx = blockIdx.x * 256 + threadIdx.x;  // total G*KK*CG*O = 589824
    if (idx >= GG * KKK * CG * OO) return;
    int o = idx & 255;
    int r = idx >> 8;          // (g*9+kk)*32 + cg
    int cg = r & 31;
    r >>= 5;                   // g*9 + kk
    int kk = r % 9;
    int g  = r / 9;
    // w_out flat: o*2304 + (g*32+cg)*9 + kk
    wt_t[idx] = w_out[o * 2304 + (g * 32 + cg) * 9 + kk];
}

// ---------------------------------------------------------------------------
// K1: direct 3x3 conv, 216 output channels (144 offset + 72 attn raw)
// grid (H, 27, B), block (64, 4). Each thread: 1 pixel x 2 consecutive oc.
// blockIdx.y covers 8 ocs -> blocks 0..17 offset-conv, 18..26 attn-conv
// (no block straddles the 144 boundary since 144 = 18*8).
// ---------------------------------------------------------------------------
__global__ __launch_bounds__(256) void conv216(
    const float* __restrict__ x,
    const float* __restrict__ w_off, const float* __restrict__ b_off,
    const float* __restrict__ w_attn, const float* __restrict__ b_attn,
    float* __restrict__ off, float* __restrict__ attn) {
    const int h = blockIdx.x;
    const int b = blockIdx.z;
    const int w = threadIdx.x;
    const int oc0 = blockIdx.y * 8 + threadIdx.y * 2;

    const float* wsrc;
    const float* bsrc;
    float* dstp;
    int ocl0;
    if (oc0 < OFFC) {
        wsrc = w_off; bsrc = b_off; ocl0 = oc0;
        dstp = off + ((long)b * OFFC + ocl0) * HW + h * WW + w;
    } else {
        wsrc = w_attn; bsrc = b_attn; ocl0 = oc0 - OFFC;
        dstp = attn + ((long)b * ATTC + ocl0) * HW + h * WW + w;
    }

    float acc0 = bsrc[ocl0];
    float acc1 = bsrc[ocl0 + 1];

    const float* xb = x + (long)b * CC * HW;
    for (int c = 0; c < CC; ++c) {
        const float* xc = xb + c * HW;
        float xv[9];
        #pragma unroll
        for (int dy = 0; dy < 3; ++dy) {
            int yy = h + dy - 1;
            bool vy = (yy >= 0) && (yy < HH);
            #pragma unroll
            for (int dx = 0; dx < 3; ++dx) {
                int xx = w + dx - 1;
                bool v = vy && (xx >= 0) && (xx < WW);
                xv[dy * 3 + dx] = v ? xc[yy * WW + xx] : 0.f;
            }
        }
        const float* wp0 = wsrc + ((long)ocl0 * CC + c) * 9;
        const float* wp1 = wp0 + (long)CC * 9;
        #pragma unroll
        for (int t = 0; t < 9; ++t) acc0 += xv[t] * wp0[t];
        #pragma unroll
        for (int t = 0; t < 9; ++t) acc1 += xv[t] * wp1[t];
    }
    dstp[0]  = acc0;
    dstp[HW] = acc1;
}

// ---------------------------------------------------------------------------
// K2: in-place softmax over the 9 kernel taps, per (b, g, h, w)
// ---------------------------------------------------------------------------
__global__ void softmax9(float* __restrict__ attn) {
    int idx = blockIdx.x * 256 + threadIdx.x;  // B*G*HW = 262144
    if (idx >= BN * GG * HW) return;
    int hw = idx & (HW - 1);
    int r = idx >> 12;   // b*G + g
    int g = r & 7;
    int b = r >> 3;
    float* p = attn + ((long)b * ATTC + g * KKK) * HW + hw;
    float v[9];
    float m = -1e30f;
    #pragma unroll
    for (int k = 0; k < 9; ++k) { v[k] = p[k * HW]; m = fmaxf(m, v[k]); }
    float s = 0.f;
    #pragma unroll
    for (int k = 0; k < 9; ++k) { v[k] = __expf(v[k] - m); s += v[k]; }
    float inv = 1.f / s;
    #pragma unroll
    for (int k = 0; k < 9; ++k) p[k * HW] = v[k] * inv;
}

// ---------------------------------------------------------------------------
// K3: fused bilinear sampling + modulation + output contraction
// grid (H, B), block 256. Block computes 64 pixels (one row) x 256 out ch.
// Per (g,kk) slab: stage A-tile [32cg][64px] (sampled*attn) and
// W-tile [32cg][256o] in LDS, then 4px x 16oc register-tile outer product.
// ---------------------------------------------------------------------------
__global__ __launch_bounds__(256) void fused_sample_gemm(
    const float* __restrict__ x, const float* __restrict__ off,
    const float* __restrict__ attn, const float* __restrict__ wt_t,
    const float* __restrict__ b_out, float* __restrict__ out) {
    __shared__ float ldsA[CG][WW];   // 8 KB
    __shared__ float ldsW[CG][OO];   // 32 KB

    const int h = blockIdx.x;
    const int b = blockIdx.y;
    const int t = threadIdx.x;
    // sampling mapping: wave = fixed cgq, lanes sweep px
    const int px  = t & 63;
    const int cgq = t >> 6;          // 0..3, covers 8 cg each
    // gemm mapping
    const int tx  = t & 15;          // px tile: px0 = tx*4
    const int ty  = t >> 4;          // oc tile: oc0 = ty*16
    const int px0 = tx * 4;
    const int oc0 = ty * 16;

    float acc[4][16];
    #pragma unroll
    for (int i = 0; i < 4; ++i)
        #pragma unroll
        for (int j = 0; j < 16; ++j) acc[i][j] = 0.f;

    const float* xb = x + (long)b * CC * HW;

    for (int g = 0; g < GG; ++g) {
        const float* xg = xb + g * CG * HW;
        for (int kk = 0; kk < KKK; ++kk) {
            // ---- stage W tile: 8192 contiguous floats, coalesced ----
            const float* wsrc = wt_t + (long)((g * KKK + kk) * CG) * OO;
            #pragma unroll
            for (int i = 0; i < 8; ++i) {
                int e = t + i * 256;  // float4 index 0..2047
                ((float4*)ldsA == nullptr) ? void(0) : void(0);
                ((float4*)(&ldsW[0][0]))[e] = ((const float4*)wsrc)[e];
            }

            // ---- sampling: compute modulated bilinear samples into ldsA ----
            int ch = (g * KKK + kk) * 2;
            float dy = off[((long)b * OFFC + ch)     * HW + h * WW + px];
            float dx = off[((long)b * OFFC + ch + 1) * HW + h * WW + px];
            float av = attn[((long)b * ATTC + g * KKK + kk) * HW + h * WW + px];

            float py  = (float)(h - 1 + kk / 3) + dy;
            float pxx = (float)(px - 1 + kk % 3) + dx;
            float y0f = floorf(py), x0f = floorf(pxx);
            int y0 = (int)y0f, x0i = (int)x0f;
            float wy1 = py - y0f, wx1 = pxx - x0f;
            float wy0 = 1.f - wy1, wx0 = 1.f - wx1;
            int y1 = y0 + 1, x1i = x0i + 1;
            bool vy0 = (y0 >= 0) && (y0 < HH);
            bool vy1 = (y1 >= 0) && (y1 < HH);
            bool vx0 = (x0i >= 0) && (x0i < WW);
            bool vx1 = (x1i >= 0) && (x1i < WW);
            int cy0 = min(max(y0, 0), HH - 1), cy1 = min(max(y1, 0), HH - 1);
            int cx0 = min(max(x0i, 0), WW - 1), cx1 = min(max(x1i, 0), WW - 1);
            float w00 = wy0 * wx0 * ((vy0 && vx0) ? 1.f : 0.f);
            float w01 = wy0 * wx1 * ((vy0 && vx1) ? 1.f : 0.f);
            float w10 = wy1 * wx0 * ((vy1 && vx0) ? 1.f : 0.f);
            float w11 = wy1 * wx1 * ((vy1 && vx1) ? 1.f : 0.f);
            int i00 = cy0 * WW + cx0, i01 = cy0 * WW + cx1;
            int i10 = cy1 * WW + cx0, i11 = cy1 * WW + cx1;

            #pragma unroll
            for (int cc = 0; cc < 8; ++cc) {
                const float* xc = xg + (cgq * 8 + cc) * HW;
                float v = w00 * xc[i00] + w01 * xc[i01]
                        + w10 * xc[i10] + w11 * xc[i11];
                ldsA[cgq * 8 + cc][px] = v * av;
            }
            __syncthreads();

            // ---- GEMM micro-step: acc[4px][16oc] += A^T W ----
            #pragma unroll 8
            for (int cg = 0; cg < CG; ++cg) {
                float4 a = *(const float4*)&ldsA[cg][px0];
                float aa[4] = {a.x, a.y, a.z, a.w};
                const float* wr = &ldsW[cg][oc0];
                float wv[16];
                #pragma unroll
                for (int jq = 0; jq < 4; ++jq) {
                    float4 wq = *(const float4*)&wr[jq * 4];
                    wv[jq * 4 + 0] = wq.x; wv[jq * 4 + 1] = wq.y;
                    wv[jq * 4 + 2] = wq.z; wv[jq * 4 + 3] = wq.w;
                }
                #pragma unroll
                for (int i = 0; i < 4; ++i)
                    #pragma unroll
                    for (int j = 0; j < 16; ++j)
                        acc[i][j] += aa[i] * wv[j];
            }
            __syncthreads();
        }
    }

    // ---- epilogue: add bias, coalesced float4 stores ----
    #pragma unroll
    for (int j = 0; j < 16; ++j) {
        int oc = oc0 + j;
        float bb = b_out[oc];
        float4 v = make_float4(acc[0][j] + bb, acc[1][j] + bb,
                               acc[2][j] + bb, acc[3][j] + bb);
        *(float4*)&out[((long)b * OO + oc) * HW + h * WW + px0] = v;
    }
}

// ---------------------------------------------------------------------------
extern "C" void kernel_launch(void* const* d_in, const int* in_sizes, int n_in,
                              void* d_out, int out_size, void* d_ws, size_t ws_size,
                              hipStream_t stream) {
    const float* x      = (const float*)d_in[0];
    const float* w_off  = (const float*)d_in[1];
    const float* b_off  = (const float*)d_in[2];
    const float* w_attn = (const float*)d_in[3];
    const float* b_attn = (const float*)d_in[4];
    const float* w_out  = (const float*)d_in[5];
    const float* b_out  = (const float*)d_in[6];
    float* out = (float*)d_out;

    // workspace layout (floats)
    float* wt_t = (float*)d_ws;                       // 589,824
    float* off  = wt_t + 589824;                      // 4,718,592
    float* attn = off + 4718592;                      // 2,359,296
    // total 30.7 MB

    // K0: repack weights
    repack_w<<<dim3((589824 + 255) / 256), dim3(256), 0, stream>>>(w_out, wt_t);

    // K1: both convs (144 offset ch + 72 attn ch)
    conv216<<<dim3(HH, 27, BN), dim3(64, 4), 0, stream>>>(
        x, w_off, b_off, w_attn, b_attn, off, attn);

    // K2: softmax over the 9 taps (in place)
    softmax9<<<dim3((BN * GG * HW) / 256), dim3(256), 0, stream>>>(attn);

    // K3: fused sampling + contraction
    fused_sample_gemm<<<dim3(HH, BN), dim3(256), 0, stream>>>(
        x, off, attn, wt_t, b_out, out);
}

// Round 2
// 1034.651 us; speedup vs baseline: 3.2681x; 3.2681x over previous
//
#include <hip/hip_runtime.h>

// Problem constants (from reference setup_inputs)
#define BN   8
#define CC   256
#define HH   64
#define WW   64
#define GG   8
#define CG   32      // C / G
#define KKK  9       // K*K
#define OO   256
#define HW   (HH*WW)
#define NPAD 224     // padded conv output channels (144 off + 72 attn + 8 zero)
#define NOUT 216     // real conv output channels

typedef __attribute__((ext_vector_type(8))) _Float16 half8;
typedef __attribute__((ext_vector_type(4))) float f32x4;

// ---------------------------------------------------------------------------
// K0a: repack w_out [O][C][3][3] -> wt_t [g][kk][cg][o]  (o contiguous, fp32)
// ---------------------------------------------------------------------------
__global__ void repack_w(const float* __restrict__ w_out, float* __restrict__ wt_t) {
    int idx = blockIdx.x * 256 + threadIdx.x;  // total G*KK*CG*O = 589824
    if (idx >= GG * KKK * CG * OO) return;
    int o = idx & 255;
    int r = idx >> 8;          // (g*9+kk)*32 + cg
    int cg = r & 31;
    r >>= 5;                   // g*9 + kk
    int kk = r % 9;
    int g  = r / 9;
    wt_t[idx] = w_out[o * 2304 + (g * 32 + cg) * 9 + kk];
}

// ---------------------------------------------------------------------------
// K0b: repack conv weights -> wt_conv f16 [tap][oc 224][c 256]; also bias[224]
// oc<144: w_off; 144<=oc<216: w_attn; else 0.
// ---------------------------------------------------------------------------
__global__ void repack_conv(const float* __restrict__ w_off, const float* __restrict__ b_off,
                            const float* __restrict__ w_attn, const float* __restrict__ b_attn,
                            _Float16* __restrict__ wt_conv, float* __restrict__ bias_c) {
    int idx = blockIdx.x * 256 + threadIdx.x;  // 9*224*256 = 516096
    if (idx >= 9 * NPAD * 256) return;
    int c = idx & 255;
    int r = idx >> 8;
    int n = r % NPAD;
    int tap = r / NPAD;
    float v = 0.f;
    if (n < 144)      v = w_off[(n * 256 + c) * 9 + tap];
    else if (n < 216) v = w_attn[((n - 144) * 256 + c) * 9 + tap];
    wt_conv[(tap * NPAD + n) * 256 + c] = (_Float16)v;
    if (idx < NPAD) {
        float bv = 0.f;
        if (idx < 144)      bv = b_off[idx];
        else if (idx < 216) bv = b_attn[idx - 144];
        bias_c[idx] = bv;
    }
}

// ---------------------------------------------------------------------------
// K1: implicit-GEMM conv via f16 MFMA. Block = 1 pixel row (M=64) x 224 oc.
// K ordering tap-major: k = tap*256 + c, staged in (tap, 32-channel) chunks.
// A_lds [64 m][40 k-pad] halves, B_lds [224 n][40 k-pad] halves.
// ---------------------------------------------------------------------------
__global__ __launch_bounds__(256) void conv_mfma(
    const float* __restrict__ x, const _Float16* __restrict__ wt_conv,
    const float* __restrict__ bias_c, float* __restrict__ conv_buf) {
    __shared__ _Float16 Ald[64 * 40];
    __shared__ _Float16 Bld[NPAD * 40];

    const int h = blockIdx.x;
    const int b = blockIdx.y;
    const int t = threadIdx.x;
    const int lane = t & 63;
    const int w = t >> 6;          // wave id = M-tile id

    f32x4 acc[14];
    #pragma unroll
    for (int i = 0; i < 14; ++i) acc[i] = (f32x4){0.f, 0.f, 0.f, 0.f};

    const float* xb = x + (long)b * CC * HW;

    // staging maps
    const int colA = t & 63;           // A: m = pixel col
    const int cA   = (t >> 6) * 8;     // A: 8 channels per thread

    for (int tap = 0; tap < 9; ++tap) {
        const int dy = tap / 3 - 1;
        const int dx = tap % 3 - 1;
        const int y  = h + dy;
        const bool vy = (y >= 0) && (y < HH);
        const int xc = colA + dx;
        const bool vx = vy && (xc >= 0) && (xc < WW);

        for (int cc = 0; cc < 8; ++cc) {
            // ---- stage A: x row (shifted) -> halves, one b128 write ----
            {
                const float* src = xb + (long)(cc * 32 + cA) * HW + y * WW + xc;
                half8 vals;
                #pragma unroll
                for (int i = 0; i < 8; ++i)
                    vals[i] = vx ? (_Float16)src[i * HW] : (_Float16)0.f;
                *(half8*)&Ald[colA * 40 + cA] = vals;
            }
            // ---- stage B: coalesced uint2 copies ----
            {
                const _Float16* wsrc = wt_conv + (long)tap * NPAD * 256 + cc * 32;
                #pragma unroll
                for (int i = 0; i < 7; ++i) {
                    int idx = t + i * 256;      // 0..1791 (224 n * 8 parts)
                    int n = idx >> 3, part = idx & 7;
                    uint2 g = *(const uint2*)(wsrc + n * 256 + part * 4);
                    *(uint2*)&Bld[n * 40 + part * 4] = g;
                }
            }
            __syncthreads();

            // ---- MFMA: 1 M-tile x 14 N-tiles ----
            const int k0 = (lane >> 4) * 8;
            half8 a = *(const half8*)&Ald[(w * 16 + (lane & 15)) * 40 + k0];
            #pragma unroll
            for (int nt = 0; nt < 14; ++nt) {
                half8 bf = *(const half8*)&Bld[(nt * 16 + (lane & 15)) * 40 + k0];
                acc[nt] = __builtin_amdgcn_mfma_f32_16x16x32_f16(a, bf, acc[nt], 0, 0, 0);
            }
            __syncthreads();
        }
    }

    // ---- epilogue: D reg walks 4 consecutive cols -> float4 stores ----
    const int colb = w * 16 + ((lane >> 4) * 4);
    #pragma unroll
    for (int nt = 0; nt < 14; ++nt) {
        int oc = nt * 16 + (lane & 15);
        if (oc < NOUT) {
            float bb = bias_c[oc];
            float4 v = make_float4(acc[nt][0] + bb, acc[nt][1] + bb,
                                   acc[nt][2] + bb, acc[nt][3] + bb);
            *(float4*)&conv_buf[((long)b * NOUT + oc) * HW + h * WW + colb] = v;
        }
    }
}

// ---------------------------------------------------------------------------
// K2: in-place softmax over the 9 kernel taps, per (b, g, h, w)
// conv_buf layout: [b][216][hw]; attn channels start at 144.
// ---------------------------------------------------------------------------
__global__ void softmax9(float* __restrict__ conv_buf) {
    int idx = blockIdx.x * 256 + threadIdx.x;  // B*G*HW = 262144
    if (idx >= BN * GG * HW) return;
    int hw = idx & (HW - 1);
    int r = idx >> 12;   // b*G + g
    int g = r & 7;
    int b = r >> 3;
    float* p = conv_buf + ((long)b * NOUT + 144 + g * KKK) * HW + hw;
    float v[9];
    float m = -1e30f;
    #pragma unroll
    for (int k = 0; k < 9; ++k) { v[k] = p[k * HW]; m = fmaxf(m, v[k]); }
    float s = 0.f;
    #pragma unroll
    for (int k = 0; k < 9; ++k) { v[k] = __expf(v[k] - m); s += v[k]; }
    float inv = 1.f / s;
    #pragma unroll
    for (int k = 0; k < 9; ++k) p[k * HW] = v[k] * inv;
}

// ---------------------------------------------------------------------------
// K3: fused bilinear sampling + modulation + output contraction (fp32)
// ---------------------------------------------------------------------------
__global__ __launch_bounds__(256) void fused_sample_gemm(
    const float* __restrict__ x, const float* __restrict__ conv_buf,
    const float* __restrict__ wt_t,
    const float* __restrict__ b_out, float* __restrict__ out) {
    __shared__ float ldsA[CG][WW];   // 8 KB
    __shared__ float ldsW[CG][OO];   // 32 KB

    const int h = blockIdx.x;
    const int b = blockIdx.y;
    const int t = threadIdx.x;
    const int px  = t & 63;
    const int cgq = t >> 6;          // 0..3, covers 8 cg each
    const int tx  = t & 15;
    const int ty  = t >> 4;
    const int px0 = tx * 4;
    const int oc0 = ty * 16;

    float acc[4][16];
    #pragma unroll
    for (int i = 0; i < 4; ++i)
        #pragma unroll
        for (int j = 0; j < 16; ++j) acc[i][j] = 0.f;

    const float* xb = x + (long)b * CC * HW;

    for (int g = 0; g < GG; ++g) {
        const float* xg = xb + g * CG * HW;
        for (int kk = 0; kk < KKK; ++kk) {
            // ---- stage W tile: 8192 contiguous floats, coalesced ----
            const float* wsrc = wt_t + (long)((g * KKK + kk) * CG) * OO;
            #pragma unroll
            for (int i = 0; i < 8; ++i) {
                int e = t + i * 256;
                ((float4*)(&ldsW[0][0]))[e] = ((const float4*)wsrc)[e];
            }

            // ---- sampling into ldsA ----
            int ch = (g * KKK + kk) * 2;
            float dy = conv_buf[((long)b * NOUT + ch)     * HW + h * WW + px];
            float dx = conv_buf[((long)b * NOUT + ch + 1) * HW + h * WW + px];
            float av = conv_buf[((long)b * NOUT + 144 + g * KKK + kk) * HW + h * WW + px];

            float py  = (float)(h - 1 + kk / 3) + dy;
            float pxx = (float)(px - 1 + kk % 3) + dx;
            float y0f = floorf(py), x0f = floorf(pxx);
            int y0 = (int)y0f, x0i = (int)x0f;
            float wy1 = py - y0f, wx1 = pxx - x0f;
            float wy0 = 1.f - wy1, wx0 = 1.f - wx1;
            int y1 = y0 + 1, x1i = x0i + 1;
            bool vy0 = (y0 >= 0) && (y0 < HH);
            bool vy1 = (y1 >= 0) && (y1 < HH);
            bool vx0 = (x0i >= 0) && (x0i < WW);
            bool vx1 = (x1i >= 0) && (x1i < WW);
            int cy0 = min(max(y0, 0), HH - 1), cy1 = min(max(y1, 0), HH - 1);
            int cx0 = min(max(x0i, 0), WW - 1), cx1 = min(max(x1i, 0), WW - 1);
            float w00 = wy0 * wx0 * ((vy0 && vx0) ? 1.f : 0.f);
            float w01 = wy0 * wx1 * ((vy0 && vx1) ? 1.f : 0.f);
            float w10 = wy1 * wx0 * ((vy1 && vx0) ? 1.f : 0.f);
            float w11 = wy1 * wx1 * ((vy1 && vx1) ? 1.f : 0.f);
            int i00 = cy0 * WW + cx0, i01 = cy0 * WW + cx1;
            int i10 = cy1 * WW + cx0, i11 = cy1 * WW + cx1;

            #pragma unroll
            for (int cc = 0; cc < 8; ++cc) {
                const float* xcp = xg + (cgq * 8 + cc) * HW;
                float v = w00 * xcp[i00] + w01 * xcp[i01]
                        + w10 * xcp[i10] + w11 * xcp[i11];
                ldsA[cgq * 8 + cc][px] = v * av;
            }
            __syncthreads();

            // ---- GEMM micro-step: acc[4px][16oc] += A^T W ----
            #pragma unroll 8
            for (int cg = 0; cg < CG; ++cg) {
                float4 a = *(const float4*)&ldsA[cg][px0];
                float aa[4] = {a.x, a.y, a.z, a.w};
                const float* wr = &ldsW[cg][oc0];
                float wv[16];
                #pragma unroll
                for (int jq = 0; jq < 4; ++jq) {
                    float4 wq = *(const float4*)&wr[jq * 4];
                    wv[jq * 4 + 0] = wq.x; wv[jq * 4 + 1] = wq.y;
                    wv[jq * 4 + 2] = wq.z; wv[jq * 4 + 3] = wq.w;
                }
                #pragma unroll
                for (int i = 0; i < 4; ++i)
                    #pragma unroll
                    for (int j = 0; j < 16; ++j)
                        acc[i][j] += aa[i] * wv[j];
            }
            __syncthreads();
        }
    }

    #pragma unroll
    for (int j = 0; j < 16; ++j) {
        int oc = oc0 + j;
        float bb = b_out[oc];
        float4 v = make_float4(acc[0][j] + bb, acc[1][j] + bb,
                               acc[2][j] + bb, acc[3][j] + bb);
        *(float4*)&out[((long)b * OO + oc) * HW + h * WW + px0] = v;
    }
}

// ---------------------------------------------------------------------------
extern "C" void kernel_launch(void* const* d_in, const int* in_sizes, int n_in,
                              void* d_out, int out_size, void* d_ws, size_t ws_size,
                              hipStream_t stream) {
    const float* x      = (const float*)d_in[0];
    const float* w_off  = (const float*)d_in[1];
    const float* b_off  = (const float*)d_in[2];
    const float* w_attn = (const float*)d_in[3];
    const float* b_attn = (const float*)d_in[4];
    const float* w_out  = (const float*)d_in[5];
    const float* b_out  = (const float*)d_in[6];
    float* out = (float*)d_out;

    // workspace layout (float units)
    float* wt_t     = (float*)d_ws;                 // 589,824 f
    float* conv_buf = wt_t + 589824;                // 8*216*4096 = 7,077,888 f
    _Float16* wt_conv = (_Float16*)(conv_buf + 7077888); // 516,096 halves
    float* bias_c   = (float*)(wt_conv + 516096);   // 224 f
    // total ~31.7 MB

    repack_w<<<dim3((589824 + 255) / 256), dim3(256), 0, stream>>>(w_out, wt_t);
    repack_conv<<<dim3((9 * NPAD * 256 + 255) / 256), dim3(256), 0, stream>>>(
        w_off, b_off, w_attn, b_attn, wt_conv, bias_c);

    conv_mfma<<<dim3(HH, BN), dim3(256), 0, stream>>>(x, wt_conv, bias_c, conv_buf);

    softmax9<<<dim3((BN * GG * HW) / 256), dim3(256), 0, stream>>>(conv_buf);

    fused_sample_gemm<<<dim3(HH, BN), dim3(256), 0, stream>>>(
        x, conv_buf, wt_t, b_out, out);
}

// Round 3
// 471.162 us; speedup vs baseline: 7.1766x; 2.1960x over previous
//
#include <hip/hip_runtime.h>

// Problem constants (from reference setup_inputs)
#define BN   8
#define CC   256
#define HH   64
#define WW   64
#define GG   8
#define CG   32      // C / G
#define KKK  9       // K*K
#define OO   256
#define HW   (HH*WW)
#define NPAD 224     // padded conv output channels (144 off + 72 attn + 8 zero)
#define NOUT 216     // real conv output channels

typedef __attribute__((ext_vector_type(8))) _Float16 half8;
typedef __attribute__((ext_vector_type(4))) _Float16 half4;
typedef __attribute__((ext_vector_type(4))) float f32x4;

// ---------------------------------------------------------------------------
// K0a: repack w_out [O][C][3][3] -> wt3 f16 [g*9+kk][o 256][cg 32]
// ---------------------------------------------------------------------------
__global__ void repack_w(const float* __restrict__ w_out, _Float16* __restrict__ wt3) {
    int idx = blockIdx.x * 256 + threadIdx.x;  // total 72*256*32 = 589824
    if (idx >= GG * KKK * CG * OO) return;
    int cg = idx & 31;
    int o  = (idx >> 5) & 255;
    int s  = idx >> 13;           // g*9 + kk
    int kk = s % 9;
    int g  = s / 9;
    wt3[idx] = (_Float16)w_out[o * 2304 + (g * 32 + cg) * 9 + kk];
}

// ---------------------------------------------------------------------------
// K0b: repack conv weights -> wt_conv f16 [tap][oc 224][c 256]; also bias[224]
// ---------------------------------------------------------------------------
__global__ void repack_conv(const float* __restrict__ w_off, const float* __restrict__ b_off,
                            const float* __restrict__ w_attn, const float* __restrict__ b_attn,
                            _Float16* __restrict__ wt_conv, float* __restrict__ bias_c) {
    int idx = blockIdx.x * 256 + threadIdx.x;  // 9*224*256 = 516096
    if (idx >= 9 * NPAD * 256) return;
    int c = idx & 255;
    int r = idx >> 8;
    int n = r % NPAD;
    int tap = r / NPAD;
    float v = 0.f;
    if (n < 144)      v = w_off[(n * 256 + c) * 9 + tap];
    else if (n < 216) v = w_attn[((n - 144) * 256 + c) * 9 + tap];
    wt_conv[(tap * NPAD + n) * 256 + c] = (_Float16)v;
    if (idx < NPAD) {
        float bv = 0.f;
        if (idx < 144)      bv = b_off[idx];
        else if (idx < 216) bv = b_attn[idx - 144];
        bias_c[idx] = bv;
    }
}

// ---------------------------------------------------------------------------
// K1: implicit-GEMM conv via f16 MFMA. Block = 512 thr (8 waves),
// M=64 px (one row) x N=224 oc. 72 stages of (tap, 32-ch chunk).
// Wave w: M-tile mt=w&3, N-tiles (w>>2)*7 .. +6.
// ---------------------------------------------------------------------------
__global__ __launch_bounds__(512, 4) void conv_mfma(
    const float* __restrict__ x, const _Float16* __restrict__ wt_conv,
    const float* __restrict__ bias_c, float* __restrict__ conv_buf) {
    __shared__ _Float16 Ald[64 * 40];      // 5 KB
    __shared__ _Float16 Bld[NPAD * 40];    // 17.5 KB

    const int h = blockIdx.x;
    const int b = blockIdx.y;
    const int t = threadIdx.x;
    const int lane = t & 63;
    const int wv = t >> 6;          // 0..7
    const int mt = wv & 3;          // M-tile
    const int nh = wv >> 2;         // N half: tiles nh*7..nh*7+6

    f32x4 acc[7];
    #pragma unroll
    for (int i = 0; i < 7; ++i) acc[i] = (f32x4){0.f, 0.f, 0.f, 0.f};

    const float* xb = x + (long)b * CC * HW;

    const int colA = t & 63;           // A: pixel col
    const int cA   = (t >> 6) * 4;     // A: 4 channels per thread

    for (int tap = 0; tap < 9; ++tap) {
        const int dy = tap / 3 - 1;
        const int dx = tap % 3 - 1;
        const int y  = h + dy;
        const bool vy = (y >= 0) && (y < HH);
        const int xc = colA + dx;
        const bool vx = vy && (xc >= 0) && (xc < WW);

        for (int cc = 0; cc < 8; ++cc) {
            // ---- stage A: shifted x row -> f16, one 8B LDS write ----
            {
                const float* src = xb + (long)(cc * 32 + cA) * HW + y * WW + xc;
                half4 vals;
                #pragma unroll
                for (int i = 0; i < 4; ++i)
                    vals[i] = vx ? (_Float16)src[i * HW] : (_Float16)0.f;
                *(half4*)&Ald[colA * 40 + cA] = vals;
            }
            // ---- stage B: 896 uint4 chunks, coalesced ----
            {
                const _Float16* wsrc = wt_conv + (long)tap * NPAD * 256 + cc * 32;
                #pragma unroll
                for (int i = 0; i < 2; ++i) {
                    int idx = t + i * 512;      // 0..1023, guard 896
                    if (idx < 896) {
                        int n = idx >> 2, part = idx & 3;
                        uint4 g4 = *(const uint4*)(wsrc + n * 256 + part * 8);
                        *(uint4*)&Bld[n * 40 + part * 8] = g4;
                    }
                }
            }
            __syncthreads();

            // ---- MFMA: 1 M-tile x 7 N-tiles per wave ----
            const int k0 = (lane >> 4) * 8;
            half8 a = *(const half8*)&Ald[(mt * 16 + (lane & 15)) * 40 + k0];
            #pragma unroll
            for (int i = 0; i < 7; ++i) {
                half8 bf = *(const half8*)&Bld[((nh * 7 + i) * 16 + (lane & 15)) * 40 + k0];
                acc[i] = __builtin_amdgcn_mfma_f32_16x16x32_f16(a, bf, acc[i], 0, 0, 0);
            }
            __syncthreads();
        }
    }

    // ---- epilogue: D reg walks 4 consecutive pixels -> float4 stores ----
    const int colb = mt * 16 + ((lane >> 4) * 4);
    #pragma unroll
    for (int i = 0; i < 7; ++i) {
        int oc = (nh * 7 + i) * 16 + (lane & 15);
        if (oc < NOUT) {
            float bb = bias_c[oc];
            float4 v = make_float4(acc[i][0] + bb, acc[i][1] + bb,
                                   acc[i][2] + bb, acc[i][3] + bb);
            *(float4*)&conv_buf[((long)b * NOUT + oc) * HW + h * WW + colb] = v;
        }
    }
}

// ---------------------------------------------------------------------------
// K2: in-place softmax over the 9 kernel taps, per (b, g, h, w)
// conv_buf layout: [b][216][hw]; attn channels start at 144.
// ---------------------------------------------------------------------------
__global__ void softmax9(float* __restrict__ conv_buf) {
    int idx = blockIdx.x * 256 + threadIdx.x;  // B*G*HW = 262144
    if (idx >= BN * GG * HW) return;
    int hw = idx & (HW - 1);
    int r = idx >> 12;   // b*G + g
    int g = r & 7;
    int b = r >> 3;
    float* p = conv_buf + ((long)b * NOUT + 144 + g * KKK) * HW + hw;
    float v[9];
    float m = -1e30f;
    #pragma unroll
    for (int k = 0; k < 9; ++k) { v[k] = p[k * HW]; m = fmaxf(m, v[k]); }
    float s = 0.f;
    #pragma unroll
    for (int k = 0; k < 9; ++k) { v[k] = __expf(v[k] - m); s += v[k]; }
    float inv = 1.f / s;
    #pragma unroll
    for (int k = 0; k < 9; ++k) p[k * HW] = v[k] * inv;
}

// ---------------------------------------------------------------------------
// K3: fused bilinear sampling + modulation + MFMA contraction.
// Block = 512 thr (8 waves), M=64 px (one row) x N=256 oc, 72 (g,kk) stages.
// Wave w: M-tiles (w&1)*2..+1, N-tiles (w>>1)*4..+3 (2 A + 4 B frags, 8 MFMA).
// ---------------------------------------------------------------------------
__global__ __launch_bounds__(512, 4) void sample_gemm_mfma(
    const float* __restrict__ x, const float* __restrict__ conv_buf,
    const _Float16* __restrict__ wt3,
    const float* __restrict__ b_out, float* __restrict__ out) {
    __shared__ _Float16 Ald[64 * 40];     // 5 KB
    __shared__ _Float16 Bld[OO * 40];     // 20 KB

    const int h = blockIdx.x;
    const int b = blockIdx.y;
    const int t = threadIdx.x;
    const int lane = t & 63;
    const int wv = t >> 6;
    const int mh = wv & 1;          // M-tiles mh*2, mh*2+1 (pixels mh*32..)
    const int nh = wv >> 1;         // N-tiles nh*4..nh*4+3

    const int px  = t & 63;
    const int cg0 = (t >> 6) * 4;   // 4 channels per thread

    f32x4 acc[2][4];
    #pragma unroll
    for (int i = 0; i < 2; ++i)
        #pragma unroll
        for (int j = 0; j < 4; ++j) acc[i][j] = (f32x4){0.f, 0.f, 0.f, 0.f};

    const float* xb = x + (long)b * CC * HW;
    const float* cb = conv_buf + (long)b * NOUT * HW + h * WW;

    for (int s = 0; s < 72; ++s) {
        const int g  = s / 9;
        const int kk = s % 9;
        const float* xg = xb + g * CG * HW;

        // ---- stage B: 1024 uint4 chunks (256 oc x 32 cg f16), coalesced ----
        {
            const _Float16* wsrc = wt3 + (long)s * OO * CG;
            #pragma unroll
            for (int i = 0; i < 2; ++i) {
                int idx = t + i * 512;      // 0..1023
                int n = idx >> 2, part = idx & 3;
                uint4 g4 = *(const uint4*)(wsrc + n * 32 + part * 8);
                *(uint4*)&Bld[n * 40 + part * 8] = g4;
            }
        }

        // ---- sampling: 4 channels per thread, offsets computed once ----
        {
            float dy = cb[(s * 2)     * HW + px];
            float dx = cb[(s * 2 + 1) * HW + px];
            float av = cb[(144 + s)   * HW + px];

            float py  = (float)(h - 1 + kk / 3) + dy;
            float pxx = (float)(px - 1 + kk % 3) + dx;
            float y0f = floorf(py), x0f = floorf(pxx);
            int y0 = (int)y0f, x0i = (int)x0f;
            float wy1 = py - y0f, wx1 = pxx - x0f;
            float wy0 = 1.f - wy1, wx0 = 1.f - wx1;
            int y1 = y0 + 1, x1i = x0i + 1;
            bool vy0 = (y0 >= 0) && (y0 < HH);
            bool vy1 = (y1 >= 0) && (y1 < HH);
            bool vx0 = (x0i >= 0) && (x0i < WW);
            bool vx1 = (x1i >= 0) && (x1i < WW);
            int cy0 = min(max(y0, 0), HH - 1), cy1 = min(max(y1, 0), HH - 1);
            int cx0 = min(max(x0i, 0), WW - 1), cx1 = min(max(x1i, 0), WW - 1);
            float w00 = wy0 * wx0 * ((vy0 && vx0) ? 1.f : 0.f) * av;
            float w01 = wy0 * wx1 * ((vy0 && vx1) ? 1.f : 0.f) * av;
            float w10 = wy1 * wx0 * ((vy1 && vx0) ? 1.f : 0.f) * av;
            float w11 = wy1 * wx1 * ((vy1 && vx1) ? 1.f : 0.f) * av;
            int i00 = cy0 * WW + cx0, i01 = cy0 * WW + cx1;
            int i10 = cy1 * WW + cx0, i11 = cy1 * WW + cx1;

            half4 vals;
            #pragma unroll
            for (int c = 0; c < 4; ++c) {
                const float* xcp = xg + (cg0 + c) * HW;
                float v = w00 * xcp[i00] + w01 * xcp[i01]
                        + w10 * xcp[i10] + w11 * xcp[i11];
                vals[c] = (_Float16)v;
            }
            *(half4*)&Ald[px * 40 + cg0] = vals;
        }
        __syncthreads();

        // ---- MFMA: 2 M-tiles x 4 N-tiles per wave ----
        const int k0 = (lane >> 4) * 8;
        half8 a0 = *(const half8*)&Ald[(mh * 32 + (lane & 15)) * 40 + k0];
        half8 a1 = *(const half8*)&Ald[(mh * 32 + 16 + (lane & 15)) * 40 + k0];
        #pragma unroll
        for (int j = 0; j < 4; ++j) {
            half8 bf = *(const half8*)&Bld[((nh * 4 + j) * 16 + (lane & 15)) * 40 + k0];
            acc[0][j] = __builtin_amdgcn_mfma_f32_16x16x32_f16(a0, bf, acc[0][j], 0, 0, 0);
            acc[1][j] = __builtin_amdgcn_mfma_f32_16x16x32_f16(a1, bf, acc[1][j], 0, 0, 0);
        }
        __syncthreads();
    }

    // ---- epilogue ----
    #pragma unroll
    for (int mi = 0; mi < 2; ++mi) {
        int px0 = mh * 32 + mi * 16 + (lane >> 4) * 4;
        #pragma unroll
        for (int j = 0; j < 4; ++j) {
            int oc = (nh * 4 + j) * 16 + (lane & 15);
            float bb = b_out[oc];
            float4 v = make_float4(acc[mi][j][0] + bb, acc[mi][j][1] + bb,
                                   acc[mi][j][2] + bb, acc[mi][j][3] + bb);
            *(float4*)&out[((long)b * OO + oc) * HW + h * WW + px0] = v;
        }
    }
}

// ---------------------------------------------------------------------------
extern "C" void kernel_launch(void* const* d_in, const int* in_sizes, int n_in,
                              void* d_out, int out_size, void* d_ws, size_t ws_size,
                              hipStream_t stream) {
    const float* x      = (const float*)d_in[0];
    const float* w_off  = (const float*)d_in[1];
    const float* b_off  = (const float*)d_in[2];
    const float* w_attn = (const float*)d_in[3];
    const float* b_attn = (const float*)d_in[4];
    const float* w_out  = (const float*)d_in[5];
    const float* b_out  = (const float*)d_in[6];
    float* out = (float*)d_out;

    // workspace layout
    float* conv_buf   = (float*)d_ws;                       // 8*216*4096 f = 7,077,888
    _Float16* wt3     = (_Float16*)(conv_buf + 7077888);    // 589,824 halves
    _Float16* wt_conv = wt3 + 589824;                       // 516,096 halves
    float* bias_c     = (float*)(wt_conv + 516096);         // 224 f
    // total ~30.5 MB

    repack_w<<<dim3((589824 + 255) / 256), dim3(256), 0, stream>>>(w_out, wt3);
    repack_conv<<<dim3((9 * NPAD * 256 + 255) / 256), dim3(256), 0, stream>>>(
        w_off, b_off, w_attn, b_attn, wt_conv, bias_c);

    conv_mfma<<<dim3(HH, BN), dim3(512), 0, stream>>>(x, wt_conv, bias_c, conv_buf);

    softmax9<<<dim3((BN * GG * HW) / 256), dim3(256), 0, stream>>>(conv_buf);

    sample_gemm_mfma<<<dim3(HH, BN), dim3(512), 0, stream>>>(
        x, conv_buf, wt3, b_out, out);
}

// Round 4
// 267.224 us; speedup vs baseline: 12.6536x; 1.7632x over previous
//
#include <hip/hip_runtime.h>

// Problem constants
#define BN   8
#define CC   256
#define HH   64
#define WW   64
#define GG   8
#define CG   32
#define KKK  9
#define OO   256
#define HW   (HH*WW)
#define NPAD 224
#define NOUT 216

typedef __attribute__((ext_vector_type(8))) _Float16 half8;
typedef __attribute__((ext_vector_type(4))) _Float16 half4;
typedef __attribute__((ext_vector_type(4))) float f32x4;

union U2H4 { uint2 u; half4 h; };

// ---------------------------------------------------------------------------
// K0a: repack w_out [O][C][3][3] -> wt3 f16 [g*9+kk][o 256][cg 32]
// ---------------------------------------------------------------------------
__global__ void repack_w(const float* __restrict__ w_out, _Float16* __restrict__ wt3) {
    int idx = blockIdx.x * 256 + threadIdx.x;
    if (idx >= GG * KKK * CG * OO) return;
    int cg = idx & 31;
    int o  = (idx >> 5) & 255;
    int s  = idx >> 13;
    int kk = s % 9;
    int g  = s / 9;
    wt3[idx] = (_Float16)w_out[o * 2304 + (g * 32 + cg) * 9 + kk];
}

// ---------------------------------------------------------------------------
// K0b: repack conv weights -> wt_conv f16 [tap][oc 224][c 256]; also bias[224]
// ---------------------------------------------------------------------------
__global__ void repack_conv(const float* __restrict__ w_off, const float* __restrict__ b_off,
                            const float* __restrict__ w_attn, const float* __restrict__ b_attn,
                            _Float16* __restrict__ wt_conv, float* __restrict__ bias_c) {
    int idx = blockIdx.x * 256 + threadIdx.x;
    if (idx >= 9 * NPAD * 256) return;
    int c = idx & 255;
    int r = idx >> 8;
    int n = r % NPAD;
    int tap = r / NPAD;
    float v = 0.f;
    if (n < 144)      v = w_off[(n * 256 + c) * 9 + tap];
    else if (n < 216) v = w_attn[((n - 144) * 256 + c) * 9 + tap];
    wt_conv[(tap * NPAD + n) * 256 + c] = (_Float16)v;
    if (idx < NPAD) {
        float bv = 0.f;
        if (idx < 144)      bv = b_off[idx];
        else if (idx < 216) bv = b_attn[idx - 144];
        bias_c[idx] = bv;
    }
}

// ---------------------------------------------------------------------------
// K0c: repack x f32 NCHW -> x_h f16 NHWC [b][y][x][c]
// Block = one (b,h) row: read 256ch x 64px coalesced, LDS transpose,
// write 64px x 512B fully coalesced.
// ---------------------------------------------------------------------------
__global__ __launch_bounds__(256) void repack_x(const float* __restrict__ x,
                                                _Float16* __restrict__ x_h) {
    __shared__ _Float16 T[64][264];
    const int bid = blockIdx.x;
    const int b = bid & 7, h = bid >> 3;
    const int t = threadIdx.x;   // = channel
    const float* src = x + (((long)(b * 256 + t)) << 12) + h * 64;
    #pragma unroll
    for (int i = 0; i < 16; ++i) {
        float4 f = ((const float4*)src)[i];
        T[i * 4 + 0][t] = (_Float16)f.x;
        T[i * 4 + 1][t] = (_Float16)f.y;
        T[i * 4 + 2][t] = (_Float16)f.z;
        T[i * 4 + 3][t] = (_Float16)f.w;
    }
    __syncthreads();
    _Float16* dst = x_h + (((long)(b * 4096 + h * 64)) << 8);
    #pragma unroll
    for (int it = 0; it < 8; ++it) {
        int idx = it * 256 + t;
        int px = idx >> 5, ch = idx & 31;
        uint4 v = *(const uint4*)&T[px][ch * 8];
        *(uint4*)(dst + px * 256 + ch * 8) = v;
    }
}

// ---------------------------------------------------------------------------
// K1: implicit-GEMM conv via f16 MFMA, software-pipelined.
// Block = (b,h) with XCD swizzle (b = bid&7). M=64 px x N=224 oc.
// 72 stages = (tap 0..8) x (32-ch chunk 0..7). Prefetch A+B regs 1 stage ahead.
// ---------------------------------------------------------------------------
__global__ __launch_bounds__(512, 4) void conv_mfma(
    const _Float16* __restrict__ x_h, const _Float16* __restrict__ wt_conv,
    const float* __restrict__ bias_c, float* __restrict__ conv_buf) {
    __shared__ _Float16 Ald[64 * 40];      // 5 KB
    __shared__ _Float16 Bld[NPAD * 40];    // 17.5 KB

    const int bid = blockIdx.x;
    const int b = bid & 7, h = bid >> 3;
    const int t = threadIdx.x;
    const int lane = t & 63;
    const int wv = t >> 6;
    const int mt = wv & 3;
    const int nh = wv >> 2;
    const int px = t >> 3, cq = t & 7;
    const bool hasB2 = (t < 384);

    f32x4 acc[7];
    #pragma unroll
    for (int i = 0; i < 7; ++i) acc[i] = (f32x4){0.f, 0.f, 0.f, 0.f};

    const _Float16* xb = x_h + ((long)b << 20) + cq * 4;
    const int bn = t >> 2, bp = (t & 3) * 8;

    // ---- preamble: issue stage 0 (tap 0: y=h-1, xc=px-1; cc=0) ----
    uint2 aReg; bool vA;
    uint4 p0, p1;
    {
        int y = h - 1, xc = px - 1;
        vA = ((unsigned)y < 64u) && ((unsigned)xc < 64u);
        int yc = min(max(y, 0), 63), xcc = min(max(xc, 0), 63);
        aReg = *(const uint2*)(xb + ((long)(yc * 64 + xcc)) * 256);
        const _Float16* ws = wt_conv;
        p0 = *(const uint4*)(ws + bn * 256 + bp);
        if (hasB2) p1 = *(const uint4*)(ws + (bn + 128) * 256 + bp);
    }

    int ti = 0, tj = 0, cc = 0;   // current-stage tap row/col, chunk
    for (int s = 0; s < 72; ++s) {
        // ---- LDS write phase from prefetched regs ----
        {
            uint2 az = vA ? aReg : make_uint2(0u, 0u);
            *(uint2*)&Ald[px * 40 + cq * 4] = az;
            *(uint4*)&Bld[bn * 40 + bp] = p0;
            if (hasB2) *(uint4*)&Bld[(bn + 128) * 40 + bp] = p1;
        }
        // ---- issue next-stage loads ----
        if (s < 71) {
            int ccn = cc + 1, tjn = tj, tin = ti;
            if (ccn == 8) { ccn = 0; tjn++; if (tjn == 3) { tjn = 0; tin++; } }
            int y = h + tin - 1, xc = px + tjn - 1;
            vA = ((unsigned)y < 64u) && ((unsigned)xc < 64u);
            int yc = min(max(y, 0), 63), xcc = min(max(xc, 0), 63);
            aReg = *(const uint2*)(xb + ((long)(yc * 64 + xcc)) * 256 + ccn * 32);
            int tapn = tin * 3 + tjn;
            const _Float16* ws = wt_conv + (long)tapn * NPAD * 256 + ccn * 32;
            p0 = *(const uint4*)(ws + bn * 256 + bp);
            if (hasB2) p1 = *(const uint4*)(ws + (bn + 128) * 256 + bp);
            cc = ccn; tj = tjn; ti = tin;
        }
        __syncthreads();

        // ---- MFMA: 1 M-tile x 7 N-tiles per wave ----
        const int k0 = (lane >> 4) * 8;
        half8 a = *(const half8*)&Ald[(mt * 16 + (lane & 15)) * 40 + k0];
        #pragma unroll
        for (int i = 0; i < 7; ++i) {
            half8 bf = *(const half8*)&Bld[((nh * 7 + i) * 16 + (lane & 15)) * 40 + k0];
            acc[i] = __builtin_amdgcn_mfma_f32_16x16x32_f16(a, bf, acc[i], 0, 0, 0);
        }
        __syncthreads();
    }

    // ---- epilogue ----
    const int colb = mt * 16 + ((lane >> 4) * 4);
    #pragma unroll
    for (int i = 0; i < 7; ++i) {
        int oc = (nh * 7 + i) * 16 + (lane & 15);
        if (oc < NOUT) {
            float bb = bias_c[oc];
            float4 v = make_float4(acc[i][0] + bb, acc[i][1] + bb,
                                   acc[i][2] + bb, acc[i][3] + bb);
            *(float4*)&conv_buf[((long)b * NOUT + oc) * HW + h * WW + colb] = v;
        }
    }
}

// ---------------------------------------------------------------------------
// K2: in-place softmax over the 9 kernel taps
// ---------------------------------------------------------------------------
__global__ void softmax9(float* __restrict__ conv_buf) {
    int idx = blockIdx.x * 256 + threadIdx.x;
    if (idx >= BN * GG * HW) return;
    int hw = idx & (HW - 1);
    int r = idx >> 12;
    int g = r & 7;
    int b = r >> 3;
    float* p = conv_buf + ((long)b * NOUT + 144 + g * KKK) * HW + hw;
    float v[9];
    float m = -1e30f;
    #pragma unroll
    for (int k = 0; k < 9; ++k) { v[k] = p[k * HW]; m = fmaxf(m, v[k]); }
    float s = 0.f;
    #pragma unroll
    for (int k = 0; k < 9; ++k) { v[k] = __expf(v[k] - m); s += v[k]; }
    float inv = 1.f / s;
    #pragma unroll
    for (int k = 0; k < 9; ++k) p[k * HW] = v[k] * inv;
}

__device__ __forceinline__ void calc_coords(int h, int px, int ki, int kj,
    float dy, float dx, float av,
    int& i00, int& i01, int& i10, int& i11,
    float& u00, float& u01, float& u10, float& u11) {
    float py  = (float)(h - 1 + ki) + dy;
    float pxf = (float)(px - 1 + kj) + dx;
    float y0f = floorf(py), x0f = floorf(pxf);
    int y0 = (int)y0f, x0 = (int)x0f;
    float wy1 = py - y0f, wx1 = pxf - x0f;
    float wy0 = 1.f - wy1, wx0 = 1.f - wx1;
    int y1 = y0 + 1, x1 = x0 + 1;
    float m00 = (((unsigned)y0 < 64u) && ((unsigned)x0 < 64u)) ? av : 0.f;
    float m01 = (((unsigned)y0 < 64u) && ((unsigned)x1 < 64u)) ? av : 0.f;
    float m10 = (((unsigned)y1 < 64u) && ((unsigned)x0 < 64u)) ? av : 0.f;
    float m11 = (((unsigned)y1 < 64u) && ((unsigned)x1 < 64u)) ? av : 0.f;
    int cy0 = min(max(y0, 0), 63), cy1 = min(max(y1, 0), 63);
    int cx0 = min(max(x0, 0), 63), cx1 = min(max(x1, 0), 63);
    u00 = wy0 * wx0 * m00; u01 = wy0 * wx1 * m01;
    u10 = wy1 * wx0 * m10; u11 = wy1 * wx1 * m11;
    i00 = cy0 * 64 + cx0; i01 = cy0 * 64 + cx1;
    i10 = cy1 * 64 + cx0; i11 = cy1 * 64 + cx1;
}

// ---------------------------------------------------------------------------
// K3: fused bilinear sampling + modulation + MFMA contraction, pipelined.
// Block = (b,h) XCD-swizzled. M=64 px x N=256 oc, 72 (g,kk) stages.
// Gathers from f16 NHWC x_h: 4 uint2 loads per thread (4 channels/corner).
// Prefetch: conv_buf values 2 stages ahead, gathers+B-tile 1 stage ahead.
// ---------------------------------------------------------------------------
__global__ __launch_bounds__(512, 4) void sample_gemm_mfma(
    const _Float16* __restrict__ x_h, const float* __restrict__ conv_buf,
    const _Float16* __restrict__ wt3,
    const float* __restrict__ b_out, float* __restrict__ out) {
    __shared__ _Float16 Ald[64 * 40];     // 5 KB
    __shared__ _Float16 Bld[OO * 40];     // 20 KB

    const int bid = blockIdx.x;
    const int b = bid & 7, h = bid >> 3;
    const int t = threadIdx.x;
    const int lane = t & 63;
    const int wv = t >> 6;
    const int mh = wv & 1;
    const int nh = wv >> 1;
    const int px = t >> 3, cq = t & 7;
    const int bn = t >> 2, bp = (t & 3) * 8;

    f32x4 acc[2][4];
    #pragma unroll
    for (int i = 0; i < 2; ++i)
        #pragma unroll
        for (int j = 0; j < 4; ++j) acc[i][j] = (f32x4){0.f, 0.f, 0.f, 0.f};

    const float* cb = conv_buf + (long)b * NOUT * HW + h * WW + px;
    const _Float16* xbase = x_h + ((long)b << 20) + cq * 4;

    // ---- pipeline state ----
    uint2 q00, q01, q10, q11;
    float u00, u01, u10, u11;
    uint4 p0, p1;
    float dyN, dxN, avN;

    // ---- preamble: stage 0 (g=0, ki=0, kj=0) ----
    {
        float dy = cb[0], dx = cb[HW], av = cb[144 * HW];
        int i00, i01, i10, i11;
        calc_coords(h, px, 0, 0, dy, dx, av, i00, i01, i10, i11, u00, u01, u10, u11);
        q00 = *(const uint2*)(xbase + (long)i00 * 256);
        q01 = *(const uint2*)(xbase + (long)i01 * 256);
        q10 = *(const uint2*)(xbase + (long)i10 * 256);
        q11 = *(const uint2*)(xbase + (long)i11 * 256);
        p0 = *(const uint4*)(wt3 + bn * 32 + bp);
        p1 = *(const uint4*)(wt3 + (bn + 128) * 32 + bp);
        dyN = cb[2 * HW]; dxN = cb[3 * HW]; avN = cb[145 * HW];
    }

    int g_c = 0, ki_c = 0, kj_c = 0;
    for (int s = 0; s < 72; ++s) {
        // ---- LDS write phase from prefetched regs ----
        {
            *(uint4*)&Bld[bn * 40 + bp] = p0;
            *(uint4*)&Bld[(bn + 128) * 40 + bp] = p1;
            U2H4 a00, a01, a10, a11;
            a00.u = q00; a01.u = q01; a10.u = q10; a11.u = q11;
            half4 r;
            #pragma unroll
            for (int c = 0; c < 4; ++c) {
                float v = u00 * (float)a00.h[c] + u01 * (float)a01.h[c]
                        + u10 * (float)a10.h[c] + u11 * (float)a11.h[c];
                r[c] = (_Float16)v;
            }
            *(half4*)&Ald[px * 40 + cq * 4] = r;
        }
        // ---- issue next-stage loads ----
        if (s < 71) {
            int kjn = kj_c + 1, kin = ki_c, gn = g_c;
            if (kjn == 3) { kjn = 0; kin++; if (kin == 3) { kin = 0; gn++; } }
            int i00, i01, i10, i11;
            calc_coords(h, px, kin, kjn, dyN, dxN, avN, i00, i01, i10, i11,
                        u00, u01, u10, u11);
            const _Float16* xg = xbase + gn * 32;
            q00 = *(const uint2*)(xg + (long)i00 * 256);
            q01 = *(const uint2*)(xg + (long)i01 * 256);
            q10 = *(const uint2*)(xg + (long)i10 * 256);
            q11 = *(const uint2*)(xg + (long)i11 * 256);
            int sn = s + 1;
            const _Float16* ws = wt3 + (long)sn * 8192;
            p0 = *(const uint4*)(ws + bn * 32 + bp);
            p1 = *(const uint4*)(ws + (bn + 128) * 32 + bp);
            int s2 = sn + 1; if (s2 > 71) s2 = 71;
            dyN = cb[(s2 * 2) * HW]; dxN = cb[(s2 * 2 + 1) * HW];
            avN = cb[(144 + s2) * HW];
            kj_c = kjn; ki_c = kin; g_c = gn;
        }
        __syncthreads();

        // ---- MFMA: 2 M-tiles x 4 N-tiles per wave ----
        const int k0 = (lane >> 4) * 8;
        half8 a0 = *(const half8*)&Ald[(mh * 32 + (lane & 15)) * 40 + k0];
        half8 a1 = *(const half8*)&Ald[(mh * 32 + 16 + (lane & 15)) * 40 + k0];
        #pragma unroll
        for (int j = 0; j < 4; ++j) {
            half8 bf = *(const half8*)&Bld[((nh * 4 + j) * 16 + (lane & 15)) * 40 + k0];
            acc[0][j] = __builtin_amdgcn_mfma_f32_16x16x32_f16(a0, bf, acc[0][j], 0, 0, 0);
            acc[1][j] = __builtin_amdgcn_mfma_f32_16x16x32_f16(a1, bf, acc[1][j], 0, 0, 0);
        }
        __syncthreads();
    }

    // ---- epilogue ----
    #pragma unroll
    for (int mi = 0; mi < 2; ++mi) {
        int px0 = mh * 32 + mi * 16 + (lane >> 4) * 4;
        #pragma unroll
        for (int j = 0; j < 4; ++j) {
            int oc = (nh * 4 + j) * 16 + (lane & 15);
            float bb = b_out[oc];
            float4 v = make_float4(acc[mi][j][0] + bb, acc[mi][j][1] + bb,
                                   acc[mi][j][2] + bb, acc[mi][j][3] + bb);
            *(float4*)&out[((long)b * OO + oc) * HW + h * WW + px0] = v;
        }
    }
}

// ---------------------------------------------------------------------------
extern "C" void kernel_launch(void* const* d_in, const int* in_sizes, int n_in,
                              void* d_out, int out_size, void* d_ws, size_t ws_size,
                              hipStream_t stream) {
    const float* x      = (const float*)d_in[0];
    const float* w_off  = (const float*)d_in[1];
    const float* b_off  = (const float*)d_in[2];
    const float* w_attn = (const float*)d_in[3];
    const float* b_attn = (const float*)d_in[4];
    const float* w_out  = (const float*)d_in[5];
    const float* b_out  = (const float*)d_in[6];
    float* out = (float*)d_out;

    // workspace layout (bytes): x_h 16.78 MB | conv_buf 28.3 MB | wt3 1.18 MB
    //                         | wt_conv 1.03 MB | bias 896 B  ~= 47.3 MB total
    _Float16* x_h     = (_Float16*)d_ws;                    // 8,388,608 halves
    float* conv_buf   = (float*)(x_h + 8388608);            // 7,077,888 floats
    _Float16* wt3     = (_Float16*)(conv_buf + 7077888);    // 589,824 halves
    _Float16* wt_conv = wt3 + 589824;                       // 516,096 halves
    float* bias_c     = (float*)(wt_conv + 516096);         // 224 floats

    repack_w<<<dim3((589824 + 255) / 256), dim3(256), 0, stream>>>(w_out, wt3);
    repack_conv<<<dim3((9 * NPAD * 256 + 255) / 256), dim3(256), 0, stream>>>(
        w_off, b_off, w_attn, b_attn, wt_conv, bias_c);
    repack_x<<<dim3(512), dim3(256), 0, stream>>>(x, x_h);

    conv_mfma<<<dim3(512), dim3(512), 0, stream>>>(x_h, wt_conv, bias_c, conv_buf);

    softmax9<<<dim3((BN * GG * HW) / 256), dim3(256), 0, stream>>>(conv_buf);

    sample_gemm_mfma<<<dim3(512), dim3(512), 0, stream>>>(
        x_h, conv_buf, wt3, b_out, out);
}